// Round 6
// baseline (290.267 us; speedup 1.0000x reference)
//
#include <hip/hip_runtime.h>
#include <hip/hip_cooperative_groups.h>
#include <math.h>

namespace cg = cooperative_groups;

#define GAMMA 0.3f
#define EPS 1e-6f
#define B_SZ 16
#define NH 32
#define KF 32768
#define KI 16384
#define KHEADS 7   // ceil(0.2 * 32)

// ---- workspace layout (float indices) ----
constexpr int OFF_MU    = 0;                    // 64  (b*4+f)
constexpr int OFF_SD    = 64;                   // 64
constexpr int OFF_RAWS  = 128;                  // 512  raw softmax denom per (b,h)
constexpr int OFF_RAWP  = 640;                  // 512  raw pos numerator
constexpr int OFF_RAWN  = 1152;                 // 512  raw neg numerator
constexpr int IOFF_BSUM = 1664;                 // 256 ints (per-2048-chunk mask counts)
constexpr int OFF_RFF   = 4096;                 // B*KF  rf expanded: rf>=0 on-mask, -1 off-mask
// total ≈ 2.1 MiB

// ---- blocks [0,64): per-(b,feat) mean/(std+eps); blocks [64,320): mask chunk counts
//      (count blocks 0..5 also zero the RAWS/RAWP/RAWN accumulators) ----
__global__ __launch_bounds__(256) void k_stats_cnt(const float* __restrict__ fC,
        const float* __restrict__ fA, const float* __restrict__ fD,
        const float* __restrict__ fB, const int* __restrict__ mask,
        float* __restrict__ ws) {
    __shared__ double r1[256], r2[256];
    __shared__ int sred[256];
    int bid = blockIdx.x, t = threadIdx.x;
    if (bid < 64) {
        int b = bid >> 2, f = bid & 3;
        const float* src;
        if (f == 0) src = fC; else if (f == 1) src = fA; else if (f == 2) src = fD; else src = fB;
        src += (size_t)b * KI;
        double s = 0.0, s2 = 0.0;
        for (int i = t; i < KI / 4; i += 256) {
            float4 v = ((const float4*)src)[i];
            s  += (double)v.x + (double)v.y + (double)v.z + (double)v.w;
            s2 += (double)v.x * v.x + (double)v.y * v.y + (double)v.z * v.z + (double)v.w * v.w;
        }
        r1[t] = s; r2[t] = s2; __syncthreads();
        for (int off = 128; off > 0; off >>= 1) {
            if (t < off) { r1[t] += r1[t + off]; r2[t] += r2[t + off]; }
            __syncthreads();
        }
        if (t == 0) {
            double mu  = r1[0] * (1.0 / KI);
            double var = fmax(r2[0] * (1.0 / KI) - mu * mu, 0.0);
            ws[OFF_MU + bid] = (float)mu;
            ws[OFF_SD + bid] = (float)(sqrt(var) + (double)EPS);
        }
    } else {
        int cblk = bid - 64;                     // 0..255, 2048 ints each
        if (cblk < 6) ws[OFF_RAWS + cblk * 256 + t] = 0.f;   // zero 1536 accum floats
        const int* mrow = mask + (size_t)cblk * 2048;
        int4 m0 = *(const int4*)(mrow + t * 8);
        int4 m1 = *(const int4*)(mrow + t * 8 + 4);
        int cnt = (m0.x != 0) + (m0.y != 0) + (m0.z != 0) + (m0.w != 0)
                + (m1.x != 0) + (m1.y != 0) + (m1.z != 0) + (m1.w != 0);
        sred[t] = cnt; __syncthreads();
        for (int off = 128; off > 0; off >>= 1) {
            if (t < off) sred[t] += sred[t + off];
            __syncthreads();
        }
        if (t == 0) ((int*)ws)[IOFF_BSUM + cblk] = sred[0];
    }
}

// ---- fused rf-compute + expand-to-full-K (rf on-mask, -1 off-mask), decoupled scan.
//      Image-token ranks of block (b,c) form the contiguous feat range [boff, boff+total),
//      so the block computes those rf values into LDS directly from the feats. ----
__global__ __launch_bounds__(256) void k_rf_expand(const float* __restrict__ fC,
        const float* __restrict__ fA, const float* __restrict__ fD,
        const float* __restrict__ fB, const int* __restrict__ mask,
        float* __restrict__ ws) {
    __shared__ int sc[256];
    __shared__ float rfbuf[2048];
    int blk = blockIdx.x, t = threadIdx.x;       // blk = b*16 + c
    int b = blk >> 4, c = blk & 15;
    const int* bsum = (const int*)ws + IOFF_BSUM;
    int boff = 0;
    for (int i = 0; i < c; ++i) boff += bsum[(b << 4) + i];
    const int* mrow = mask + (size_t)blk * 2048;
    int4 m0 = *(const int4*)(mrow + t * 8);
    int4 m1 = *(const int4*)(mrow + t * 8 + 4);
    int mv[8] = {m0.x, m0.y, m0.z, m0.w, m1.x, m1.y, m1.z, m1.w};
    int cnt = 0;
    #pragma unroll
    for (int j = 0; j < 8; ++j) cnt += (mv[j] != 0);
    sc[t] = cnt; __syncthreads();
    for (int off = 1; off < 256; off <<= 1) {
        int v = (t >= off) ? sc[t - off] : 0;
        __syncthreads();
        sc[t] += v;
        __syncthreads();
    }
    int total = sc[255];
    int rloc = sc[t] - cnt;                      // local rank of my first element
    // cooperative rf for ranks [boff, boff+total)
    float mu0 = ws[OFF_MU + b * 4 + 0], sd0 = ws[OFF_SD + b * 4 + 0];
    float mu1 = ws[OFF_MU + b * 4 + 1], sd1 = ws[OFF_SD + b * 4 + 1];
    float mu2 = ws[OFF_MU + b * 4 + 2], sd2 = ws[OFF_SD + b * 4 + 2];
    float mu3 = ws[OFF_MU + b * 4 + 3], sd3 = ws[OFF_SD + b * 4 + 3];
    for (int j = t; j < total; j += 256) {
        size_t idx = (size_t)b * KI + boff + j;
        float Ct = fmaxf((fC[idx] - mu0) / sd0, 0.f);
        float At = 1.f / (1.f + __expf(-((fA[idx] - mu1) / sd1)));
        float Dt = 1.f / (1.f + __expf(-((fD[idx] - mu2) / sd2)));
        float Bt = 1.f / (1.f + __expf(-((fB[idx] - mu3) / sd3)));
        float denom = fmaxf(1.f + 0.5f * (Dt + Bt), EPS);
        rfbuf[j] = fmaxf(Ct * At / denom, 0.f);
    }
    __syncthreads();
    float vr[8];
    #pragma unroll
    for (int j = 0; j < 8; ++j) {
        if (mv[j]) { vr[j] = rfbuf[rloc]; ++rloc; }
        else       { vr[j] = -1.f; }
    }
    float* rff = ws + OFF_RFF + (size_t)blk * 2048 + t * 8;
    *(float4*)(rff)     = *(float4*)(vr);
    *(float4*)(rff + 4) = *(float4*)(vr + 4);
}

// ---- helpers shared by fused and fallback paths ----
__device__ __forceinline__ void score_accum(const float* __restrict__ xr,
        const float* __restrict__ rff, int t, float& S, float& P, float& N) {
    #pragma unroll 4
    for (int i = 0; i < 16; ++i) {
        int k = (i * 256 + t) * 4;
        float4 xs = *(const float4*)(xr + k);
        float4 rv = *(const float4*)(rff + k);
        float xa[4] = {xs.x, xs.y, xs.z, xs.w};
        float va[4] = {rv.x, rv.y, rv.z, rv.w};
        #pragma unroll
        for (int j = 0; j < 4; ++j) {
            float e = __expf(xa[j]);
            bool on = va[j] >= 0.f;
            float rfv  = fmaxf(va[j], 0.f);
            float lrfv = on ? fmaxf(1.f - va[j], 0.f) : 0.f;
            S += on ? e : 0.f;
            P = fmaf(e, rfv, P);
            N = fmaf(e, lrfv, N);
        }
    }
}

// jax top_k semantics: value desc, tie -> lower index, strictly-positive only.
// Computes gp/gn for head h of batch b into *gp,*gn (call with full block).
__device__ __forceinline__ void topk_gains(const float* __restrict__ ws,
        unsigned int b, unsigned int h, unsigned int t, float* gp_out, float* gn_out) {
    __shared__ float ssp[NH], snv[NH];
    __shared__ int smp[NH];
    __shared__ float s_gp, s_gn;
    if (t < NH) {
        float S0 = ws[OFF_RAWS + b * NH + t];
        ssp[t] = ws[OFF_RAWP + b * NH + t] / S0;
        snv[t] = ws[OFF_RAWN + b * NH + t] / S0;
    }
    __syncthreads();
    if (t < NH) {
        float sp = ssp[t];
        int cnt = 0;
        for (int j = 0; j < NH; ++j) { float o = ssp[j]; cnt += (o > sp) || (o == sp && j < (int)t); }
        smp[t] = (cnt < KHEADS) && (sp > 0.f);
    }
    __syncthreads();
    if (t < NH && smp[t]) snv[t] = -INFINITY;
    __syncthreads();
    if (t == 0) {
        float gp = 0.f, gn = 0.f;
        if (smp[h]) gp = GAMMA;
        else {
            float nv = snv[h];
            int cnt = 0;
            for (int j = 0; j < NH; ++j) { float o = snv[j]; cnt += (o > nv) || (o == nv && j < (int)h); }
            if ((cnt < KHEADS) && (nv > 0.f)) gn = GAMMA;
        }
        s_gp = gp; s_gn = gn;
    }
    __syncthreads();
    *gp_out = s_gp; *gn_out = s_gn;
}

// ---- cooperative fused: scores -> grid.sync -> topk -> apply+write.
//      1024 blocks x 256; low VGPR (attn re-read in phase 3, LLC-warm). ----
__global__ __launch_bounds__(256) void k_fused(const float* __restrict__ attn,
        float* __restrict__ ws, float* __restrict__ out) {
    cg::grid_group grid = cg::this_grid();
    int g = blockIdx.x, t = threadIdx.x;
    int bh = g >> 1, half = g & 1;
    unsigned int b = bh >> 5, h = bh & 31;
    size_t abase = ((size_t)bh << 15) + ((size_t)half << 14);
    size_t rbase = ((size_t)b  << 15) + ((size_t)half << 14);
    const float* xr  = attn + abase;
    const float* rff = ws + OFF_RFF + rbase;

    float S = 0.f, P = 0.f, N = 0.f;
    score_accum(xr, rff, t, S, P, N);
    __shared__ float rs[256], rp[256], rn[256];
    rs[t] = S; rp[t] = P; rn[t] = N;
    __syncthreads();
    for (int off = 128; off > 0; off >>= 1) {
        if (t < off) { rs[t] += rs[t + off]; rp[t] += rp[t + off]; rn[t] += rn[t + off]; }
        __syncthreads();
    }
    if (t == 0) {
        atomicAdd(&ws[OFF_RAWS + bh], rs[0]);
        atomicAdd(&ws[OFF_RAWP + bh], rp[0]);
        atomicAdd(&ws[OFF_RAWN + bh], rn[0]);
    }

    grid.sync();

    float gp, gn;
    topk_gains(ws, b, h, t, &gp, &gn);

    float* orow = out + abase;
    #pragma unroll 4
    for (int i = 0; i < 16; ++i) {
        int k = (i * 256 + t) * 4;
        float4 xs = *(const float4*)(xr + k);      // LLC-warm re-read
        float4 rv = *(const float4*)(rff + k);
        float xa[4] = {xs.x, xs.y, xs.z, xs.w};
        float va[4] = {rv.x, rv.y, rv.z, rv.w};
        float oa[4];
        #pragma unroll
        for (int j = 0; j < 4; ++j) {
            bool on = va[j] >= 0.f;
            float rfv  = fmaxf(va[j], 0.f);
            float lrfv = on ? fmaxf(1.f - va[j], 0.f) : 0.f;
            oa[j] = xa[j] + gp * rfv - gn * lrfv;
        }
        float4 o = {oa[0], oa[1], oa[2], oa[3]};
        *(float4*)(orow + k) = o;
    }
}

// ---- fallback pair (R5-proven) ----
__global__ __launch_bounds__(256) void k_scores(const float* __restrict__ attn,
                                                float* __restrict__ ws) {
    int g = blockIdx.x, t = threadIdx.x;         // 1024 blocks: bh = g>>1, half = g&1
    int bh = g >> 1, half = g & 1;
    int b = bh >> 5;
    const float* xr  = attn + ((size_t)bh << 15) + ((size_t)half << 14);
    const float* rff = ws + OFF_RFF + ((size_t)b << 15) + ((size_t)half << 14);
    float S = 0.f, P = 0.f, N = 0.f;
    score_accum(xr, rff, t, S, P, N);
    __shared__ float rs[256], rp[256], rn[256];
    rs[t] = S; rp[t] = P; rn[t] = N;
    __syncthreads();
    for (int off = 128; off > 0; off >>= 1) {
        if (t < off) { rs[t] += rs[t + off]; rp[t] += rp[t + off]; rn[t] += rn[t + off]; }
        __syncthreads();
    }
    if (t == 0) {
        atomicAdd(&ws[OFF_RAWS + bh], rs[0]);
        atomicAdd(&ws[OFF_RAWP + bh], rp[0]);
        atomicAdd(&ws[OFF_RAWN + bh], rn[0]);
    }
}

__global__ __launch_bounds__(256) void k_out(const float* __restrict__ attn,
        const float* __restrict__ ws, float* __restrict__ out) {
    unsigned int t = threadIdx.x;
    unsigned int flat = (blockIdx.x * 256 + t) * 4;   // grid covers exactly B*H*KF/4
    unsigned int bh = flat >> 15;                     // uniform per block
    unsigned int b  = bh >> 5;
    unsigned int h  = bh & 31;
    float gp, gn;
    topk_gains(ws, b, h, t, &gp, &gn);
    const float* rff = ws + OFF_RFF + ((size_t)b << 15);
    unsigned int k = flat & (KF - 1);
    float4 xs = *(const float4*)(attn + flat);
    float4 rv = *(const float4*)(rff + k);
    float va[4] = {rv.x, rv.y, rv.z, rv.w};
    float xa[4] = {xs.x, xs.y, xs.z, xs.w};
    float oa[4];
    #pragma unroll
    for (int j = 0; j < 4; ++j) {
        bool on = va[j] >= 0.f;
        float rfv  = fmaxf(va[j], 0.f);
        float lrfv = on ? fmaxf(1.f - va[j], 0.f) : 0.f;
        oa[j] = xa[j] + gp * rfv - gn * lrfv;
    }
    float4 o = {oa[0], oa[1], oa[2], oa[3]};
    *(float4*)(out + flat) = o;
}

extern "C" void kernel_launch(void* const* d_in, const int* in_sizes, int n_in,
                              void* d_out, int out_size, void* d_ws, size_t ws_size,
                              hipStream_t stream) {
    const float* attn = (const float*)d_in[0];   // f32 [B,H,KF]
    const int*   mask = (const int*)d_in[1];     // int32 [B,KF]
    const float* fC   = (const float*)d_in[2];   // f32 [B,KI]
    const float* fA   = (const float*)d_in[3];
    const float* fD   = (const float*)d_in[4];
    const float* fB   = (const float*)d_in[5];
    float* out = (float*)d_out;                  // f32 [B,H,KF]
    float* ws = (float*)d_ws;

    k_stats_cnt<<<320, 256, 0, stream>>>(fC, fA, fD, fB, mask, ws);
    k_rf_expand<<<256, 256, 0, stream>>>(fC, fA, fD, fB, mask, ws);

    void* args[] = {(void*)&attn, (void*)&ws, (void*)&out};
    hipError_t e = hipLaunchCooperativeKernel((void*)k_fused, dim3(1024), dim3(256),
                                              args, 0, stream);
    if (e != hipSuccess) {
        (void)hipGetLastError();                 // clear sticky error, take proven path
        k_scores<<<1024, 256, 0, stream>>>(attn, ws);
        k_out<<<(B_SZ * NH * KF / 4) / 256, 256, 0, stream>>>(attn, ws, out);
    }
}

// Round 7
// 153.088 us; speedup vs baseline: 1.8961x; 1.8961x over previous
//
#include <hip/hip_runtime.h>
#include <math.h>

#define GAMMA 0.3f
#define EPS 1e-6f
#define B_SZ 16
#define NH 32
#define KF 32768
#define KI 16384
#define KHEADS 7   // ceil(0.2 * 32)

// ---- workspace layout (float indices) ----
constexpr int OFF_MU    = 0;                    // 64  (b*4+f)
constexpr int OFF_SD    = 64;                   // 64
constexpr int OFF_RAWS  = 128;                  // 512  raw softmax denom per (b,h)
constexpr int OFF_RAWP  = 640;                  // 512  raw pos numerator
constexpr int OFF_RAWN  = 1152;                 // 512  raw neg numerator
constexpr int IOFF_BSUM = 1664;                 // 256 ints (per-2048-chunk mask counts)
constexpr int OFF_RFF   = 4096;                 // B*KF  rf expanded: rf>=0 on-mask, -1 off-mask
// total ≈ 2.1 MiB

// NOTE (R6 lesson): do NOT fuse via hipLaunchCooperativeKernel/grid.sync() —
// measured ~120 µs barrier cost on gfx950 (k_fused 151 µs vs ~32 µs of work).
// Separate dispatches are the cheap grid barrier.

// ---- blocks [0,64): per-(b,feat) mean/(std+eps); blocks [64,320): mask chunk counts
//      (count blocks 0..5 also zero the RAWS/RAWP/RAWN accumulators) ----
__global__ __launch_bounds__(256) void k_stats_cnt(const float* __restrict__ fC,
        const float* __restrict__ fA, const float* __restrict__ fD,
        const float* __restrict__ fB, const int* __restrict__ mask,
        float* __restrict__ ws) {
    __shared__ double r1[256], r2[256];
    __shared__ int sred[256];
    int bid = blockIdx.x, t = threadIdx.x;
    if (bid < 64) {
        int b = bid >> 2, f = bid & 3;
        const float* src;
        if (f == 0) src = fC; else if (f == 1) src = fA; else if (f == 2) src = fD; else src = fB;
        src += (size_t)b * KI;
        double s = 0.0, s2 = 0.0;
        for (int i = t; i < KI / 4; i += 256) {
            float4 v = ((const float4*)src)[i];
            s  += (double)v.x + (double)v.y + (double)v.z + (double)v.w;
            s2 += (double)v.x * v.x + (double)v.y * v.y + (double)v.z * v.z + (double)v.w * v.w;
        }
        r1[t] = s; r2[t] = s2; __syncthreads();
        for (int off = 128; off > 0; off >>= 1) {
            if (t < off) { r1[t] += r1[t + off]; r2[t] += r2[t + off]; }
            __syncthreads();
        }
        if (t == 0) {
            double mu  = r1[0] * (1.0 / KI);
            double var = fmax(r2[0] * (1.0 / KI) - mu * mu, 0.0);
            ws[OFF_MU + bid] = (float)mu;
            ws[OFF_SD + bid] = (float)(sqrt(var) + (double)EPS);
        }
    } else {
        int cblk = bid - 64;                     // 0..255, 2048 ints each
        if (cblk < 6) ws[OFF_RAWS + cblk * 256 + t] = 0.f;   // zero 1536 accum floats
        const int* mrow = mask + (size_t)cblk * 2048;
        int4 m0 = *(const int4*)(mrow + t * 8);
        int4 m1 = *(const int4*)(mrow + t * 8 + 4);
        int cnt = (m0.x != 0) + (m0.y != 0) + (m0.z != 0) + (m0.w != 0)
                + (m1.x != 0) + (m1.y != 0) + (m1.z != 0) + (m1.w != 0);
        sred[t] = cnt; __syncthreads();
        for (int off = 128; off > 0; off >>= 1) {
            if (t < off) sred[t] += sred[t + off];
            __syncthreads();
        }
        if (t == 0) ((int*)ws)[IOFF_BSUM + cblk] = sred[0];
    }
}

// ---- fused rf-compute + expand-to-full-K (rf on-mask, -1 off-mask), decoupled scan.
//      Image-token ranks of block (b,c) form the contiguous feat range [boff, boff+total),
//      so the block computes those rf values into LDS directly from the feats. ----
__global__ __launch_bounds__(256) void k_rf_expand(const float* __restrict__ fC,
        const float* __restrict__ fA, const float* __restrict__ fD,
        const float* __restrict__ fB, const int* __restrict__ mask,
        float* __restrict__ ws) {
    __shared__ int sc[256];
    __shared__ float rfbuf[2048];
    int blk = blockIdx.x, t = threadIdx.x;       // blk = b*16 + c
    int b = blk >> 4, c = blk & 15;
    const int* bsum = (const int*)ws + IOFF_BSUM;
    int boff = 0;
    for (int i = 0; i < c; ++i) boff += bsum[(b << 4) + i];
    const int* mrow = mask + (size_t)blk * 2048;
    int4 m0 = *(const int4*)(mrow + t * 8);
    int4 m1 = *(const int4*)(mrow + t * 8 + 4);
    int mv[8] = {m0.x, m0.y, m0.z, m0.w, m1.x, m1.y, m1.z, m1.w};
    int cnt = 0;
    #pragma unroll
    for (int j = 0; j < 8; ++j) cnt += (mv[j] != 0);
    sc[t] = cnt; __syncthreads();
    for (int off = 1; off < 256; off <<= 1) {
        int v = (t >= off) ? sc[t - off] : 0;
        __syncthreads();
        sc[t] += v;
        __syncthreads();
    }
    int total = sc[255];
    int rloc = sc[t] - cnt;                      // local rank of my first element
    float mu0 = ws[OFF_MU + b * 4 + 0], sd0 = ws[OFF_SD + b * 4 + 0];
    float mu1 = ws[OFF_MU + b * 4 + 1], sd1 = ws[OFF_SD + b * 4 + 1];
    float mu2 = ws[OFF_MU + b * 4 + 2], sd2 = ws[OFF_SD + b * 4 + 2];
    float mu3 = ws[OFF_MU + b * 4 + 3], sd3 = ws[OFF_SD + b * 4 + 3];
    for (int j = t; j < total; j += 256) {
        size_t idx = (size_t)b * KI + boff + j;
        float Ct = fmaxf((fC[idx] - mu0) / sd0, 0.f);
        float At = 1.f / (1.f + __expf(-((fA[idx] - mu1) / sd1)));
        float Dt = 1.f / (1.f + __expf(-((fD[idx] - mu2) / sd2)));
        float Bt = 1.f / (1.f + __expf(-((fB[idx] - mu3) / sd3)));
        float denom = fmaxf(1.f + 0.5f * (Dt + Bt), EPS);
        rfbuf[j] = fmaxf(Ct * At / denom, 0.f);
    }
    __syncthreads();
    float vr[8];
    #pragma unroll
    for (int j = 0; j < 8; ++j) {
        if (mv[j]) { vr[j] = rfbuf[rloc]; ++rloc; }
        else       { vr[j] = -1.f; }
    }
    float* rff = ws + OFF_RFF + (size_t)blk * 2048 + t * 8;
    *(float4*)(rff)     = *(float4*)(vr);
    *(float4*)(rff + 4) = *(float4*)(vr + 4);
}

// ---- per-(b,h)-half raw masked-softmax accumulation (branchless, no max-sub: |x|<~6,
//      e^x <= ~300 so no overflow; raw sums combined via atomicAdd) ----
__global__ __launch_bounds__(256) void k_scores(const float* __restrict__ attn,
                                                float* __restrict__ ws) {
    int g = blockIdx.x, t = threadIdx.x;         // 1024 blocks: bh = g>>1, half = g&1
    int bh = g >> 1, half = g & 1;
    int b = bh >> 5;
    const float* xr  = attn + ((size_t)bh << 15) + ((size_t)half << 14);
    const float* rff = ws + OFF_RFF + ((size_t)b << 15) + ((size_t)half << 14);
    float S = 0.f, P = 0.f, N = 0.f;
    #pragma unroll 4
    for (int i = 0; i < 16; ++i) {
        int k = (i * 256 + t) * 4;
        float4 xs = *(const float4*)(xr + k);
        float4 rv = *(const float4*)(rff + k);
        float xa[4] = {xs.x, xs.y, xs.z, xs.w};
        float va[4] = {rv.x, rv.y, rv.z, rv.w};
        #pragma unroll
        for (int j = 0; j < 4; ++j) {
            float e = __expf(xa[j]);
            bool on = va[j] >= 0.f;
            float rfv  = fmaxf(va[j], 0.f);
            float lrfv = on ? fmaxf(1.f - va[j], 0.f) : 0.f;
            S += on ? e : 0.f;
            P = fmaf(e, rfv, P);
            N = fmaf(e, lrfv, N);
        }
    }
    __shared__ float rs[256], rp[256], rn[256];
    rs[t] = S; rp[t] = P; rn[t] = N;
    __syncthreads();
    for (int off = 128; off > 0; off >>= 1) {
        if (t < off) { rs[t] += rs[t + off]; rp[t] += rp[t + off]; rn[t] += rn[t + off]; }
        __syncthreads();
    }
    if (t == 0) {
        atomicAdd(&ws[OFF_RAWS + bh], rs[0]);
        atomicAdd(&ws[OFF_RAWP + bh], rp[0]);
        atomicAdd(&ws[OFF_RAWN + bh], rn[0]);
    }
}

// ---- out = attn + gp*rf - gn*low_rf; per-block redundant top-k (jax top_k semantics:
//      value desc, tie -> lower index, strictly-positive only). 8 elems/thread. ----
__global__ __launch_bounds__(256) void k_out(const float* __restrict__ attn,
        const float* __restrict__ ws, float* __restrict__ out) {
    unsigned int t = threadIdx.x;
    unsigned int flat = blockIdx.x * 2048 + t * 8;    // 8192 blocks x 2048 elems
    unsigned int bh = flat >> 15;                     // uniform per block (2048 | 32768)
    unsigned int b  = bh >> 5;
    unsigned int h  = bh & 31;

    __shared__ float ssp[NH], snv[NH];
    __shared__ int smp[NH];
    __shared__ float s_gp, s_gn;
    if (t < NH) {
        float S0 = ws[OFF_RAWS + b * NH + t];
        ssp[t] = ws[OFF_RAWP + b * NH + t] / S0;
        snv[t] = ws[OFF_RAWN + b * NH + t] / S0;
    }
    __syncthreads();
    if (t < NH) {
        float sp = ssp[t];
        int cnt = 0;
        for (int j = 0; j < NH; ++j) { float o = ssp[j]; cnt += (o > sp) || (o == sp && j < (int)t); }
        smp[t] = (cnt < KHEADS) && (sp > 0.f);
    }
    __syncthreads();
    if (t < NH && smp[t]) snv[t] = -INFINITY;
    __syncthreads();
    if (t == 0) {
        float gp = 0.f, gn = 0.f;
        if (smp[h]) gp = GAMMA;
        else {
            float nv = snv[h];
            int cnt = 0;
            for (int j = 0; j < NH; ++j) { float o = snv[j]; cnt += (o > nv) || (o == nv && j < (int)h); }
            if ((cnt < KHEADS) && (nv > 0.f)) gn = GAMMA;
        }
        s_gp = gp; s_gn = gn;
    }
    __syncthreads();

    float gp = s_gp, gn = s_gn;
    const float* rff = ws + OFF_RFF + ((size_t)b << 15);
    unsigned int k = flat & (KF - 1);
    #pragma unroll
    for (int half8 = 0; half8 < 2; ++half8) {
        unsigned int f2 = flat + half8 * 4, k2 = k + half8 * 4;
        float4 xs = *(const float4*)(attn + f2);
        float4 rv = *(const float4*)(rff + k2);
        float va[4] = {rv.x, rv.y, rv.z, rv.w};
        float xa[4] = {xs.x, xs.y, xs.z, xs.w};
        float oa[4];
        #pragma unroll
        for (int j = 0; j < 4; ++j) {
            bool on = va[j] >= 0.f;
            float rfv  = fmaxf(va[j], 0.f);
            float lrfv = on ? fmaxf(1.f - va[j], 0.f) : 0.f;
            oa[j] = xa[j] + gp * rfv - gn * lrfv;
        }
        float4 o = {oa[0], oa[1], oa[2], oa[3]};
        *(float4*)(out + f2) = o;
    }
}

extern "C" void kernel_launch(void* const* d_in, const int* in_sizes, int n_in,
                              void* d_out, int out_size, void* d_ws, size_t ws_size,
                              hipStream_t stream) {
    const float* attn = (const float*)d_in[0];   // f32 [B,H,KF]
    const int*   mask = (const int*)d_in[1];     // int32 [B,KF]
    const float* fC   = (const float*)d_in[2];   // f32 [B,KI]
    const float* fA   = (const float*)d_in[3];
    const float* fD   = (const float*)d_in[4];
    const float* fB   = (const float*)d_in[5];
    float* out = (float*)d_out;                  // f32 [B,H,KF]
    float* ws = (float*)d_ws;

    k_stats_cnt<<<320, 256, 0, stream>>>(fC, fA, fD, fB, mask, ws);
    k_rf_expand<<<256, 256, 0, stream>>>(fC, fA, fD, fB, mask, ws);
    k_scores   <<<1024, 256, 0, stream>>>(attn, ws);
    k_out      <<<B_SZ * NH * KF / 2048, 256, 0, stream>>>(attn, ws, out);
}